// Round 9
// baseline (2059.268 us; speedup 1.0000x reference)
//
#include <hip/hip_runtime.h>
#include <math.h>

// XFADS: N=32, T=1024, D_OBS=128, D_Z=64, D_U=8, H_ENC=256, H_BW=128, H_DYN=256, D_A=128
#define T_LEN 1024
#define NB 32

typedef _Float16 f16x8 __attribute__((ext_vector_type(8)));
typedef _Float16 f16x4 __attribute__((ext_vector_type(4)));
typedef float f32x4 __attribute__((ext_vector_type(4)));

__device__ __forceinline__ float softplus_f(float x) {
    return fmaxf(x, 0.f) + log1pf(expf(-fabsf(x)));
}

__device__ __forceinline__ float fast_tanh(float x) {
    float e = __builtin_amdgcn_exp2f(x * 2.88539008177792681472f);
    float r = __builtin_amdgcn_rcpf(1.f + e);
    return 1.f - 2.f * r;
}

// raw barrier: drain LDS ops only; global prefetches stay in flight (T4 pattern)
__device__ __forceinline__ void bar_sync() {
    asm volatile("s_waitcnt lgkmcnt(0)" ::: "memory");
    __builtin_amdgcn_s_barrier();
    asm volatile("" ::: "memory");
}

// swizzled f16-row addressing: row b (stride R f16), element idx.
// chunk(8 f16) XOR (b&7) -> b128 reads / b64 writes land 2-way max (free).
#define SWZ(b, R, idx) ((b)*(R) + ((((idx) >> 3) ^ ((b) & 7)) << 3) + ((idx) & 7))

// -------------------------------------------------------------------------
// K1: encoder  h = tanh(y@W1+b1); a = h@W2+b2;
//     apre[t][n][:] = a@bw_wa + bw_b
//     preU[t][n][:] = u@dyn_w1[64:72] + dyn_b1
// -------------------------------------------------------------------------
__global__ __launch_bounds__(256) void k_encoder(
    const float* __restrict__ y, const float* __restrict__ u,
    const float* __restrict__ w1, const float* __restrict__ b1,
    const float* __restrict__ w2, const float* __restrict__ b2,
    const float* __restrict__ wa, const float* __restrict__ bb,
    const float* __restrict__ dynw1, const float* __restrict__ dynb1,
    float* __restrict__ apre, float* __restrict__ preU)
{
    __shared__ float ly[8][128];
    __shared__ float lh[8][256];
    __shared__ float la[8][128];
    __shared__ float lu[8][8];
    const int tid = threadIdx.x;
    const int row0 = blockIdx.x * 8;

    ((float4*)&ly[0][0])[tid] = ((const float4*)(y + (size_t)row0 * 128))[tid];
    if (tid < 16)
        ((float4*)&lu[0][0])[tid] = ((const float4*)(u + (size_t)row0 * 8))[tid];
    __syncthreads();

    {
        float acc[8] = {0,0,0,0,0,0,0,0};
        for (int i = 0; i < 128; i += 4) {
            float w0 = w1[(i+0)*256 + tid];
            float w1v = w1[(i+1)*256 + tid];
            float w2v = w1[(i+2)*256 + tid];
            float w3 = w1[(i+3)*256 + tid];
            #pragma unroll
            for (int r = 0; r < 8; ++r) {
                float4 yv = *(const float4*)&ly[r][i];
                acc[r] += yv.x*w0 + yv.y*w1v + yv.z*w2v + yv.w*w3;
            }
        }
        float bias = b1[tid];
        #pragma unroll
        for (int r = 0; r < 8; ++r) lh[r][tid] = fast_tanh(acc[r] + bias);
    }
    __syncthreads();

    {
        const int d = tid & 127, rh = tid >> 7;
        float acc[4] = {0,0,0,0};
        for (int i = 0; i < 256; i += 4) {
            float w0 = w2[(i+0)*128 + d];
            float w1v = w2[(i+1)*128 + d];
            float w2v = w2[(i+2)*128 + d];
            float w3 = w2[(i+3)*128 + d];
            #pragma unroll
            for (int q = 0; q < 4; ++q) {
                float4 hv = *(const float4*)&lh[rh*4+q][i];
                acc[q] += hv.x*w0 + hv.y*w1v + hv.z*w2v + hv.w*w3;
            }
        }
        float bias = b2[d];
        #pragma unroll
        for (int q = 0; q < 4; ++q) la[rh*4+q][d] = acc[q] + bias;
    }
    __syncthreads();

    {
        const int j = tid & 127, rh = tid >> 7;
        float acc[4] = {0,0,0,0};
        for (int i = 0; i < 128; i += 4) {
            float w0 = wa[(i+0)*128 + j];
            float w1v = wa[(i+1)*128 + j];
            float w2v = wa[(i+2)*128 + j];
            float w3 = wa[(i+3)*128 + j];
            #pragma unroll
            for (int q = 0; q < 4; ++q) {
                float4 av = *(const float4*)&la[rh*4+q][i];
                acc[q] += av.x*w0 + av.y*w1v + av.z*w2v + av.w*w3;
            }
        }
        float bias = bb[j];
        #pragma unroll
        for (int q = 0; q < 4; ++q) {
            int rn = row0 + rh*4 + q;
            int n = rn >> 10, t = rn & 1023;
            apre[((size_t)t*NB + n)*128 + j] = acc[q] + bias;
        }
    }

    {
        float wu[8];
        #pragma unroll
        for (int c = 0; c < 8; ++c) wu[c] = dynw1[(64 + c)*256 + tid];
        float bias = dynb1[tid];
        #pragma unroll
        for (int r = 0; r < 8; ++r) {
            float acc = bias;
            #pragma unroll
            for (int c = 0; c < 8; ++c) acc += lu[r][c] * wu[c];
            int rn = row0 + r;
            int n = rn >> 10, t = rn & 1023;
            preU[((size_t)t*NB + n)*256 + tid] = acc;
        }
    }
}

// -------------------------------------------------------------------------
// K2: backward scan via TRANSPOSED MFMA: H'^T = tanh(apre^T + Wh^T @ H^T).
// 2 blocks x 16 batches, 4 waves. D[row=j][col=batch].
// A = Wh^T frags in regs (wave w owns j-tiles 2w,2w+1; 8 x f16x8).
// B = H stored [batch][128] f16, swizzled; lane reads contiguous b128.
// Epilogue: lane owns 4 consecutive j at batch c -> f16x4 LDS write +
// float4 hcell store. H double-buffered -> ONE barrier/step.
// -------------------------------------------------------------------------
__global__ __launch_bounds__(256, 1) void k_bwscan(
    const float* __restrict__ apre, const float* __restrict__ wh,
    float* __restrict__ hcell)
{
    const int nb = blockIdx.x * 16;
    const int tid = threadIdx.x;
    const int w = tid >> 6, l = tid & 63;
    const int g = l >> 4, c = l & 15;
    __shared__ __align__(16) _Float16 Hl[2][16 * 128];

    // A frags: Af[jj][kt], elem i = Wh^T[(2w+jj)*16+c][kt*32+g*8+i] = wh[k][j]
    f16x8 Af[2][4];
    #pragma unroll
    for (int jj = 0; jj < 2; ++jj)
        #pragma unroll
        for (int kt = 0; kt < 4; ++kt) {
            f16x8 v;
            #pragma unroll
            for (int i = 0; i < 8; ++i)
                v[i] = (_Float16)wh[(size_t)(kt*32 + g*8 + i)*128 + (2*w + jj)*16 + c];
            Af[jj][kt] = v;
        }

    for (int e = tid; e < 16 * 128; e += 256) Hl[0][e] = (_Float16)0.f;
    __syncthreads();

    float4 ap[2];
    #pragma unroll
    for (int jj = 0; jj < 2; ++jj)
        ap[jj] = *(const float4*)&apre[((size_t)1023*NB + nb + c)*128 + (2*w + jj)*16 + g*4];

    int cur = 0;
    for (int t = 1023; t >= 0; --t) {
        float4 apN[2] = {{0,0,0,0},{0,0,0,0}};
        if (t > 0) {
            #pragma unroll
            for (int jj = 0; jj < 2; ++jj)
                apN[jj] = *(const float4*)&apre[((size_t)(t-1)*NB + nb + c)*128 + (2*w + jj)*16 + g*4];
        }

        // B frags: contiguous b128 from swizzled H rows (2-way banks = free)
        f16x8 b0 = *(const f16x8*)&Hl[cur][SWZ(c, 128, 0*32 + g*8)];
        f16x8 b1 = *(const f16x8*)&Hl[cur][SWZ(c, 128, 1*32 + g*8)];
        f16x8 b2 = *(const f16x8*)&Hl[cur][SWZ(c, 128, 2*32 + g*8)];
        f16x8 b3 = *(const f16x8*)&Hl[cur][SWZ(c, 128, 3*32 + g*8)];

        #pragma unroll
        for (int jj = 0; jj < 2; ++jj) {
            f32x4 aA = {0.f,0.f,0.f,0.f}, aB = {0.f,0.f,0.f,0.f};
            aA = __builtin_amdgcn_mfma_f32_16x16x32_f16(Af[jj][0], b0, aA, 0, 0, 0);
            aB = __builtin_amdgcn_mfma_f32_16x16x32_f16(Af[jj][1], b1, aB, 0, 0, 0);
            aA = __builtin_amdgcn_mfma_f32_16x16x32_f16(Af[jj][2], b2, aA, 0, 0, 0);
            aB = __builtin_amdgcn_mfma_f32_16x16x32_f16(Af[jj][3], b3, aB, 0, 0, 0);
            f32x4 acc = aA + aB;

            const int j0 = (2*w + jj)*16 + g*4;     // 4 consecutive j
            float4 hc;
            f16x4 hh;
            #pragma unroll
            for (int r = 0; r < 4; ++r) {
                float v = fast_tanh(acc[r] + ((const float*)&ap[jj])[r]);
                ((float*)&hc)[r] = v;
                hh[r] = (_Float16)v;
            }
            *(f16x4*)&Hl[cur ^ 1][SWZ(c, 128, j0)] = hh;
            *(float4*)&hcell[((size_t)t*NB + nb + c)*128 + j0] = hc;
        }
        bar_sync();
        cur ^= 1;
        ap[0] = apN[0]; ap[1] = apN[1];
    }
}

// -------------------------------------------------------------------------
// K3: b = hcell @ wo + bo; alpha = [b[:64], -softplus(b[64:])]
// -------------------------------------------------------------------------
__global__ __launch_bounds__(256) void k_alpha(
    const float* __restrict__ hcell, const float* __restrict__ wo,
    const float* __restrict__ bo, float* __restrict__ alpha)
{
    __shared__ float lhc[8][128];
    const int tid = threadIdx.x;
    const size_t base = (size_t)blockIdx.x * 8 * 128;
    ((float4*)&lhc[0][0])[tid] = ((const float4*)(hcell + base))[tid];
    __syncthreads();

    const int j = tid & 127, rh = tid >> 7;
    float acc[4] = {0,0,0,0};
    for (int i = 0; i < 128; i += 4) {
        float w0 = wo[(i+0)*128 + j];
        float w1v = wo[(i+1)*128 + j];
        float w2v = wo[(i+2)*128 + j];
        float w3 = wo[(i+3)*128 + j];
        #pragma unroll
        for (int q = 0; q < 4; ++q) {
            float4 hv = *(const float4*)&lhc[rh*4+q][i];
            acc[q] += hv.x*w0 + hv.y*w1v + hv.z*w2v + hv.w*w3;
        }
    }
    float bias = bo[j];
    #pragma unroll
    for (int q = 0; q < 4; ++q) {
        float b = acc[q] + bias;
        float val = (j < 64) ? b : -softplus_f(b);
        alpha[base + (size_t)(rh*4+q)*128 + j] = val;
    }
}

// -------------------------------------------------------------------------
// K4: forward scan via TRANSPOSED MFMA. 2 blocks x 16 batches, 4 waves.
// G1: HID^T = tanh(preU^T + W1m^T @ M^T)  — wave w owns h-tiles 4w..4w+3.
// G2: PRED^T = W2^T @ HID^T              — wave w owns d-tile w; 2-par accs.
// Lane epilogue owns 4 consecutive d at batch c: float4 out stores,
// f16x4 M write. M single-buffered, 2 barriers/step.
// -------------------------------------------------------------------------
__global__ __launch_bounds__(256, 1) void k_fwscan(
    const float* __restrict__ alpha, const float* __restrict__ preU,
    const float* __restrict__ dynw1, const float* __restrict__ dynw2,
    const float* __restrict__ dynb2, const float* __restrict__ qraw,
    const float* __restrict__ m0, const float* __restrict__ v0,
    float* __restrict__ out)
{
    const int nb = blockIdx.x * 16;
    const int tid = threadIdx.x;
    const int w = tid >> 6, l = tid & 63;
    const int g = l >> 4, c = l & 15;
    __shared__ __align__(16) _Float16 Mld[16 * 64];
    __shared__ __align__(16) _Float16 Hidl[16 * 256];

    // A1 frags: W1^T, wave w owns h-tiles (w*4+hti): elem i = dynw1[k][h]
    f16x8 A1[4][2];
    #pragma unroll
    for (int hti = 0; hti < 4; ++hti)
        #pragma unroll
        for (int kt = 0; kt < 2; ++kt) {
            f16x8 v;
            #pragma unroll
            for (int i = 0; i < 8; ++i)
                v[i] = (_Float16)dynw1[(size_t)(kt*32 + g*8 + i)*256 + (w*4 + hti)*16 + c];
            A1[hti][kt] = v;
        }
    // A2 frags: W2^T, wave w owns d-tile w: elem i = dynw2[k][d]
    f16x8 A2[8];
    #pragma unroll
    for (int kt = 0; kt < 8; ++kt) {
        f16x8 v;
        #pragma unroll
        for (int i = 0; i < 8; ++i)
            v[i] = (_Float16)dynw2[(size_t)(kt*32 + g*8 + i)*64 + w*16 + c];
        A2[kt] = v;
    }

    const int d0 = w*16 + g*4;                 // 4 consecutive d per lane
    float4 q4  = *(const float4*)&qraw[d0];
    float4 b2v = *(const float4*)&dynb2[d0];
    float4 vreg = *(const float4*)&v0[d0];
    float4 Qv;
    #pragma unroll
    for (int r = 0; r < 4; ++r) ((float*)&Qv)[r] = softplus_f(((const float*)&q4)[r]);

    for (int e = tid; e < 1024; e += 256) {
        int b = e >> 6, dd = e & 63;
        Mld[SWZ(b, 64, dd)] = (_Float16)m0[dd];
    }
    __syncthreads();

    // prefetch t=0
    float4 hp[4];
    #pragma unroll
    for (int hti = 0; hti < 4; ++hti)
        hp[hti] = *(const float4*)&preU[((size_t)nb + c)*256 + (w*4 + hti)*16 + g*4];
    float4 al1 = *(const float4*)&alpha[((size_t)nb + c)*128 + d0];
    float4 al2 = *(const float4*)&alpha[((size_t)nb + c)*128 + 64 + d0];

    for (int t = 0; t < T_LEN; ++t) {
        float4 hpN[4] = {{0,0,0,0},{0,0,0,0},{0,0,0,0},{0,0,0,0}};
        float4 al1N = {0,0,0,0}, al2N = {0,0,0,0};
        if (t + 1 < T_LEN) {
            #pragma unroll
            for (int hti = 0; hti < 4; ++hti)
                hpN[hti] = *(const float4*)&preU[((size_t)(t+1)*NB + nb + c)*256 + (w*4 + hti)*16 + g*4];
            al1N = *(const float4*)&alpha[((size_t)(t+1)*NB + nb + c)*128 + d0];
            al2N = *(const float4*)&alpha[((size_t)(t+1)*NB + nb + c)*128 + 64 + d0];
        }

        // G1: B frags from M (contiguous b128, swizzled)
        f16x8 bm0 = *(const f16x8*)&Mld[SWZ(c, 64, 0*32 + g*8)];
        f16x8 bm1 = *(const f16x8*)&Mld[SWZ(c, 64, 1*32 + g*8)];
        #pragma unroll
        for (int hti = 0; hti < 4; ++hti) {
            f32x4 aA = {0.f,0.f,0.f,0.f}, aB = {0.f,0.f,0.f,0.f};
            aA = __builtin_amdgcn_mfma_f32_16x16x32_f16(A1[hti][0], bm0, aA, 0, 0, 0);
            aB = __builtin_amdgcn_mfma_f32_16x16x32_f16(A1[hti][1], bm1, aB, 0, 0, 0);
            f32x4 acc = aA + aB;
            const int h0 = (w*4 + hti)*16 + g*4;   // 4 consecutive h
            f16x4 hh;
            #pragma unroll
            for (int r = 0; r < 4; ++r)
                hh[r] = (_Float16)fast_tanh(((const float*)&hp[hti])[r] + acc[r]);
            *(f16x4*)&Hidl[SWZ(c, 256, h0)] = hh;
        }
        bar_sync();   // HID ready; M reads done

        // G2: 8 k-tiles, 2 parallel accumulator chains
        f32x4 aA = {0.f,0.f,0.f,0.f}, aB = {0.f,0.f,0.f,0.f};
        #pragma unroll
        for (int kt = 0; kt < 8; kt += 2) {
            f16x8 h0 = *(const f16x8*)&Hidl[SWZ(c, 256, kt*32 + g*8)];
            f16x8 h1 = *(const f16x8*)&Hidl[SWZ(c, 256, (kt+1)*32 + g*8)];
            aA = __builtin_amdgcn_mfma_f32_16x16x32_f16(A2[kt],   h0, aA, 0, 0, 0);
            aB = __builtin_amdgcn_mfma_f32_16x16x32_f16(A2[kt+1], h1, aB, 0, 0, 0);
        }
        f32x4 acc2 = aA + aB;

        // epilogue: batch c, d = d0..d0+3
        float4 oms, ovs, omp, ovp;
        f16x4 mm;
        #pragma unroll
        for (int r = 0; r < 4; ++r) {
            float m_p = acc2[r] + ((const float*)&b2v)[r];
            float v_p = ((const float*)&vreg)[r] + ((const float*)&Qv)[r];
            float rvp = __builtin_amdgcn_rcpf(v_p);
            float e1 = m_p * rvp + ((const float*)&al1)[r];
            float e2 = ((const float*)&al2)[r] - 0.5f * rvp;
            float v_s = -0.5f * __builtin_amdgcn_rcpf(e2);
            float m_s = v_s * e1;
            ((float*)&vreg)[r] = v_s;
            ((float*)&oms)[r] = m_s; ((float*)&ovs)[r] = v_s;
            ((float*)&omp)[r] = m_p; ((float*)&ovp)[r] = v_p;
            mm[r] = (_Float16)m_s;
        }
        *(f16x4*)&Mld[SWZ(c, 64, d0)] = mm;
        size_t ob = ((size_t)(nb + c)*T_LEN + t)*256;
        *(float4*)&out[ob + d0]        = oms;
        *(float4*)&out[ob + 64 + d0]   = ovs;
        *(float4*)&out[ob + 128 + d0]  = omp;
        *(float4*)&out[ob + 192 + d0]  = ovp;

        bar_sync();   // M update visible before next G1 reads
        #pragma unroll
        for (int hti = 0; hti < 4; ++hti) hp[hti] = hpN[hti];
        al1 = al1N; al2 = al2N;
    }
}

// -------------------------------------------------------------------------
extern "C" void kernel_launch(void* const* d_in, const int* in_sizes, int n_in,
                              void* d_out, int out_size, void* d_ws, size_t ws_size,
                              hipStream_t stream) {
    const float* y      = (const float*)d_in[1];
    const float* u      = (const float*)d_in[2];
    const float* enc_w1 = (const float*)d_in[3];
    const float* enc_b1 = (const float*)d_in[4];
    const float* enc_w2 = (const float*)d_in[5];
    const float* enc_b2 = (const float*)d_in[6];
    const float* bw_wa  = (const float*)d_in[7];
    const float* bw_wh  = (const float*)d_in[8];
    const float* bw_b   = (const float*)d_in[9];
    const float* bw_wo  = (const float*)d_in[10];
    const float* bw_bo  = (const float*)d_in[11];
    const float* dyn_w1 = (const float*)d_in[12];
    const float* dyn_b1 = (const float*)d_in[13];
    const float* dyn_w2 = (const float*)d_in[14];
    const float* dyn_b2 = (const float*)d_in[15];
    const float* q_raw  = (const float*)d_in[16];
    const float* m0     = (const float*)d_in[17];
    const float* v0     = (const float*)d_in[18];
    float* out = (float*)d_out;

    float* ws = (float*)d_ws;
    float* apre  = ws;                  // [T*NB][128]
    float* hcell = ws + 4194304;        // [T*NB][128]
    float* alpha = ws;                  // aliases apre (apre dead after K2)
    float* preU  = ws + 2 * 4194304;    // [T*NB][256]

    k_encoder<<<4096, 256, 0, stream>>>(y, u, enc_w1, enc_b1, enc_w2, enc_b2,
                                        bw_wa, bw_b, dyn_w1, dyn_b1, apre, preU);
    k_bwscan<<<2, 256, 0, stream>>>(apre, bw_wh, hcell);
    k_alpha<<<4096, 256, 0, stream>>>(hcell, bw_wo, bw_bo, alpha);
    k_fwscan<<<2, 256, 0, stream>>>(alpha, preU, dyn_w1, dyn_w2, dyn_b2,
                                    q_raw, m0, v0, out);
}